// Round 3
// baseline (147259.900 us; speedup 1.0000x reference)
//
#include <hip/hip_runtime.h>
#include <hip/hip_bf16.h>
#include <hip/hip_fp16.h>

// Persistent dataflow RNN for MI355X.
//   SEQ=4096, HID=2048, 4 layers. 256 WGs (1/CU), 64 per layer, 32 rows each.
//   Weights held in VGPRs as fp16 MFMA A-fragments (64 VGPRs/lane).
//   Cross-WG sync: per-WG monotonic step counters, agent-scope release/acquire.
//
// R3 change: pin weight fragments in VGPRs with empty inline asm. R1/R2 showed
// the compiler sinks/spills the 64-VGPR weight array into the t-loop
// (VGPR_Count=56, FETCH 73 MB/step ~= re-streaming all weights every step).
// asm volatile("" : "+v"(frag)) makes the loaded values opaque: loads cannot
// be rematerialized or sunk, so weights stay register-resident across the
// 4096-step loop. Fragments stored as f32x4 (4-VGPR "v" tuple), bit-cast to
// f16x8 at MFMA time (free).

#define SEQ 4096
#define HID 2048
#define NL 4
#define WGS_PER_LAYER 64
#define ROWS_PER_WG 32
#define KCAT 4096      // concat(x, h)
#define NTILE 16       // 16 MFMAs (k=32 each) per wave per step: 512 k per wave

typedef _Float16 f16x8 __attribute__((ext_vector_type(8)));
typedef float f32x4 __attribute__((ext_vector_type(4)));

// Static device buffers (avoid ws_size assumptions). Re-initialized every call.
__device__ __align__(16) _Float16 g_xin[(size_t)SEQ * HID];        // 16 MB
__device__ __align__(16) _Float16 g_ring[NL][SEQ][HID];            // 67 MB history
__device__ int g_flags[NL][WGS_PER_LAYER];                         // steps completed

__global__ void prep_kernel(const float* __restrict__ x) {
  size_t i = (size_t)blockIdx.x * blockDim.x + threadIdx.x;
  if (blockIdx.x == 0 && threadIdx.x < NL * WGS_PER_LAYER)
    ((int*)g_flags)[threadIdx.x] = 0;
  if (i < (size_t)SEQ * HID) g_xin[i] = (_Float16)x[i];
}

__global__ __launch_bounds__(1024, 4) void rnn_kernel(
    const float* __restrict__ wih, const float* __restrict__ whh,
    float* __restrict__ out) {
  const int layer = blockIdx.x & 3;   // interleave layers across XCD round-robin
  const int wg    = blockIdx.x >> 2;  // 0..63 within layer
  const int tid   = threadIdx.x;
  const int lane  = tid & 63;
  const int wave  = tid >> 6;         // 16 waves
  const int rb    = wave & 1;         // row block (16 rows each)
  const int kr    = wave >> 1;        // k range 0..7 (512 k each)
  const int m     = lane & 15;
  const int q     = lane >> 4;
  const int row   = wg * ROWS_PER_WG + rb * 16 + m;  // weight row this lane holds

  __shared__ __align__(16) _Float16 cat[KCAT];       // [0,2048)=x_t  [2048,4096)=h_{t-1}
  __shared__ __align__(16) float partials[16][16];   // [kr*2+rb][row within 32.. as 2x16]

  // ---- one-time: weights -> registers as fp16 A-fragments ----
  // A layout (16x16x32): lane holds A[m = lane&15][k = ktile + q*8 + j], j=0..7
  f32x4 afrag[NTILE];  // bit-container for f16x8 fragments (4 VGPRs each)
  {
    const float* wl = wih + (size_t)layer * HID * HID + (size_t)row * HID;
    const float* wr = whh + (size_t)layer * HID * HID + (size_t)row * HID - HID;
#pragma unroll
    for (int i = 0; i < NTILE; ++i) {
      int kabs = kr * 512 + i * 32 + q * 8;          // multiple of 8; tiles never straddle 2048
      const float* src = (kabs < HID) ? (wl + kabs) : (wr + kabs);
      f32x4 w0 = *(const f32x4*)(src);
      f32x4 w1 = *(const f32x4*)(src + 4);
      f16x8 a;
      a[0] = (_Float16)w0[0]; a[1] = (_Float16)w0[1];
      a[2] = (_Float16)w0[2]; a[3] = (_Float16)w0[3];
      a[4] = (_Float16)w1[0]; a[5] = (_Float16)w1[1];
      a[6] = (_Float16)w1[2]; a[7] = (_Float16)w1[3];
      afrag[i] = __builtin_bit_cast(f32x4, a);
    }
    // Pin: make values opaque so the loads above cannot be sunk into the
    // t-loop or rematerialized; forces register residency for the session.
#pragma unroll
    for (int i = 0; i < NTILE; ++i) asm volatile("" : "+v"(afrag[i]));
  }

  bool bailed = false;  // safety: never hang the harness

  for (int t = 0; t < SEQ; ++t) {
    // ---- wait for own h_{t-1} (all 64 WGs >= t) and prev layer x_t (>= t+1) ----
    if (tid < 64 && !bailed) {
      int spin = 0;
      for (;;) {
        int fo = __hip_atomic_load(&g_flags[layer][lane], __ATOMIC_RELAXED,
                                   __HIP_MEMORY_SCOPE_AGENT);
        bool ok = (fo >= t);
        if (layer > 0) {
          int fp = __hip_atomic_load(&g_flags[layer - 1][lane], __ATOMIC_RELAXED,
                                     __HIP_MEMORY_SCOPE_AGENT);
          ok = ok && (fp >= t + 1);
        }
        if (__ballot(ok) == ~0ull) break;
        if (++spin > (1 << 22)) { bailed = true; break; }
        __builtin_amdgcn_s_sleep(1);
      }
    }
    __syncthreads();
    __builtin_amdgcn_fence(__ATOMIC_ACQUIRE, "agent");  // all threads: inv stale caches

    // ---- stage concat(x_t, h_{t-1}) into LDS: 8 KB, one uint2 per thread ----
    if (tid < 512) {
      const uint2* src = (layer == 0)
          ? (const uint2*)(g_xin + (size_t)t * HID)
          : (const uint2*)(&g_ring[layer - 1][t][0]);
      ((uint2*)cat)[tid] = src[tid];
    } else {
      uint2 v = make_uint2(0u, 0u);
      if (t > 0) v = ((const uint2*)(&g_ring[layer][t - 1][0]))[tid - 512];
      ((uint2*)cat)[tid] = v;
    }
    __syncthreads();

    // ---- MFMA: rows (16) x own k-range (512). B = h broadcast to all 16 cols ----
    f32x4 acc0 = {0.f, 0.f, 0.f, 0.f}, acc1 = {0.f, 0.f, 0.f, 0.f};
    const f16x8* bb = (const f16x8*)cat;  // 16B units
#pragma unroll
    for (int i = 0; i < NTILE; i += 2) {
      f16x8 b0 = bb[kr * 64 + i * 4 + q];
      f16x8 b1 = bb[kr * 64 + (i + 1) * 4 + q];
      acc0 = __builtin_amdgcn_mfma_f32_16x16x32_f16(
          __builtin_bit_cast(f16x8, afrag[i]), b0, acc0, 0, 0, 0);
      acc1 = __builtin_amdgcn_mfma_f32_16x16x32_f16(
          __builtin_bit_cast(f16x8, afrag[i + 1]), b1, acc1, 0, 0, 0);
    }
    f32x4 accs = acc0 + acc1;
    // D layout: col=lane&15 (all cols equal here), row=(lane>>4)*4+reg
    if (m == 0) *(f32x4*)&partials[kr * 2 + rb][q * 4] = accs;
    __syncthreads();

    // ---- reduce 8 k-partials per row, relu, publish ----
    if (tid < ROWS_PER_WG) {
      int rbb = tid >> 4, rr = tid & 15;
      float s = 0.f;
#pragma unroll
      for (int k = 0; k < 8; ++k) s += partials[k * 2 + rbb][rr];
      s = fmaxf(s, 0.f);
      int gr = wg * ROWS_PER_WG + tid;
      g_ring[layer][t][gr] = (_Float16)s;
      if (layer == NL - 1) {
        out[(size_t)t * HID + gr] = s;                       // output[0, t, :]
        if (t == SEQ - 1) out[(size_t)SEQ * HID + gr] = s;   // h_last
      }
    }
    __syncthreads();  // drains vmcnt: slice stores complete before flag release

    if (tid == 0)
      __hip_atomic_store(&g_flags[layer][wg], t + 1, __ATOMIC_RELEASE,
                         __HIP_MEMORY_SCOPE_AGENT);
  }
}

extern "C" void kernel_launch(void* const* d_in, const int* in_sizes, int n_in,
                              void* d_out, int out_size, void* d_ws, size_t ws_size,
                              hipStream_t stream) {
  const float* x   = (const float*)d_in[0];
  const float* wih = (const float*)d_in[1];
  const float* whh = (const float*)d_in[2];
  float* out = (float*)d_out;

  prep_kernel<<<(SEQ * HID + 1023) / 1024, 1024, 0, stream>>>(x);
  rnn_kernel<<<NL * WGS_PER_LAYER, 1024, 0, stream>>>(wih, whh, out);
}

// Round 5
// 16673.260 us; speedup vs baseline: 8.8321x; 8.8321x over previous
//
#include <hip/hip_runtime.h>
#include <hip/hip_bf16.h>
#include <hip/hip_fp16.h>

// Persistent dataflow RNN for MI355X (gfx950).
//   SEQ=4096, HID=2048, 4 layers. 256 WGs (1 per CU), 64 per layer, 32 rows each.
//
// R5 = R4 with two fixes:
//  - g_ring typed as u64 (8-B static alignment) so u32/u64 atomic casts are
//    legal (-Watomic-alignment was a hard error).
//  - staging loads 16 B/thread (512 threads x 16 B = 8 KB = full cat); R4
//    only filled half.
// Design (from R3 evidence): 512 threads (8 waves), __launch_bounds__(512,2)
// -> 256-VGPR cap; 128 VGPRs/lane of pinned fp16 weight fragments; NO fences
// in the loop — all cross-WG data moves via relaxed agent-scope (sc1)
// atomics that are IC-coherent across XCDs; producer orders data-before-flag
// with explicit s_waitcnt vmcnt(0).

#define SEQ 4096
#define HID 2048
#define NL 4
#define WGS_PER_LAYER 64
#define ROWS_PER_WG 32
#define KCAT 4096      // concat(x, h) elements
#define NT 32          // MFMA k-tiles per wave (k=1024 per wave, 4 k-ranges)

typedef _Float16 f16x8 __attribute__((ext_vector_type(8)));
typedef float f32x4 __attribute__((ext_vector_type(4)));
typedef unsigned long long u64;

__device__ __align__(16) _Float16 g_xin[(size_t)SEQ * HID];      // 16 MB
__device__ __align__(16) u64 g_ring[NL][SEQ][HID / 4];           // 67 MB (fp16 packed)
__device__ int g_flags[NL][WGS_PER_LAYER];                       // steps completed

__global__ void prep_kernel(const float* __restrict__ x) {
  size_t i = (size_t)blockIdx.x * blockDim.x + threadIdx.x;
  if (blockIdx.x == 0 && threadIdx.x < NL * WGS_PER_LAYER)
    ((int*)g_flags)[threadIdx.x] = 0;
  if (i < (size_t)SEQ * HID) g_xin[i] = (_Float16)x[i];
}

__global__ __launch_bounds__(512, 2) void rnn_kernel(
    const float* __restrict__ wih, const float* __restrict__ whh,
    float* __restrict__ out) {
  const int layer = blockIdx.x & 3;
  const int wg    = blockIdx.x >> 2;  // 0..63 within layer
  const int tid   = threadIdx.x;
  const int lane  = tid & 63;
  const int wave  = tid >> 6;         // 8 waves
  const int rb    = wave >> 2;        // row block: 0 -> rows 0..15, 1 -> 16..31
  const int kq    = wave & 3;         // k-range 0..3 (1024 k each)
  const int m     = lane & 15;
  const int q     = lane >> 4;
  const int row   = wg * ROWS_PER_WG + rb * 16 + m;

  __shared__ __align__(16) _Float16 cat[KCAT];      // [0,2048)=x_t [2048,4096)=h_{t-1}
  __shared__ __align__(16) float partials[8][16];   // [wave][row-in-16]

  // ---- one-time: weights -> registers as fp16 A-fragments (128 VGPRs) ----
  // A layout (16x16x32): lane holds A[m][ktile + q*8 + j], j=0..7
  f32x4 afrag[NT];
  {
    const float* wl = wih + (size_t)layer * HID * HID + (size_t)row * HID;
    const float* wr = whh + (size_t)layer * HID * HID + (size_t)row * HID - HID;
#pragma unroll
    for (int i = 0; i < NT; ++i) {
      int kabs = kq * 1024 + i * 32 + q * 8;   // 1024-aligned ranges: never straddle 2048
      const float* src = (kabs < HID) ? (wl + kabs) : (wr + kabs);
      f32x4 w0 = *(const f32x4*)(src);
      f32x4 w1 = *(const f32x4*)(src + 4);
      f16x8 a;
      a[0] = (_Float16)w0[0]; a[1] = (_Float16)w0[1];
      a[2] = (_Float16)w0[2]; a[3] = (_Float16)w0[3];
      a[4] = (_Float16)w1[0]; a[5] = (_Float16)w1[1];
      a[6] = (_Float16)w1[2]; a[7] = (_Float16)w1[3];
      afrag[i] = __builtin_bit_cast(f32x4, a);
    }
#pragma unroll
    for (int i = 0; i < NT; ++i) asm volatile("" : "+v"(afrag[i]));  // pin
  }

  bool bailed = false;

  for (int t = 0; t < SEQ; ++t) {
    // ---- wave 0: wait for own layer h_{t-1} (all 64 WGs >= t) and prev x_t ----
    if (tid < 64 && !bailed) {
      int spin = 0;
      for (;;) {
        int fo = __hip_atomic_load(&g_flags[layer][lane], __ATOMIC_RELAXED,
                                   __HIP_MEMORY_SCOPE_AGENT);
        bool ok = (fo >= t);
        if (layer > 0) {
          int fp = __hip_atomic_load(&g_flags[layer - 1][lane], __ATOMIC_RELAXED,
                                     __HIP_MEMORY_SCOPE_AGENT);
          ok = ok && (fp >= t + 1);
        }
        if (__ballot(ok) == ~0ull) break;
        if (++spin > (1 << 22)) { bailed = true; break; }
        __builtin_amdgcn_s_sleep(1);
      }
    }
    __syncthreads();
    asm volatile("" ::: "memory");  // no fence: coherence is per-access (sc1)

    // ---- stage concat(x_t, h_{t-1}) into LDS: 512 threads x 16 B ----
    {
      u64 v0 = 0, v1 = 0;
      if (tid < 256) {
        if (layer == 0) {
          const u64* src = (const u64*)(g_xin + (size_t)t * HID);
          v0 = src[2 * tid];
          v1 = src[2 * tid + 1];
        } else {
          v0 = __hip_atomic_load(&g_ring[layer - 1][t][2 * tid],
                                 __ATOMIC_RELAXED, __HIP_MEMORY_SCOPE_AGENT);
          v1 = __hip_atomic_load(&g_ring[layer - 1][t][2 * tid + 1],
                                 __ATOMIC_RELAXED, __HIP_MEMORY_SCOPE_AGENT);
        }
      } else if (t > 0) {
        int i = tid - 256;
        v0 = __hip_atomic_load(&g_ring[layer][t - 1][2 * i],
                               __ATOMIC_RELAXED, __HIP_MEMORY_SCOPE_AGENT);
        v1 = __hip_atomic_load(&g_ring[layer][t - 1][2 * i + 1],
                               __ATOMIC_RELAXED, __HIP_MEMORY_SCOPE_AGENT);
      }
      ((u64*)cat)[2 * tid]     = v0;
      ((u64*)cat)[2 * tid + 1] = v1;
    }
    __syncthreads();

    // ---- MFMA: 16 rows x own 1024-k range. B = h broadcast to 16 cols ----
    f32x4 acc0 = {0.f, 0.f, 0.f, 0.f}, acc1 = {0.f, 0.f, 0.f, 0.f};
    const f16x8* bb = (const f16x8*)cat;
#pragma unroll
    for (int i = 0; i < NT; i += 2) {
      f16x8 b0 = bb[kq * 128 + i * 4 + q];
      f16x8 b1 = bb[kq * 128 + (i + 1) * 4 + q];
      acc0 = __builtin_amdgcn_mfma_f32_16x16x32_f16(
          __builtin_bit_cast(f16x8, afrag[i]), b0, acc0, 0, 0, 0);
      acc1 = __builtin_amdgcn_mfma_f32_16x16x32_f16(
          __builtin_bit_cast(f16x8, afrag[i + 1]), b1, acc1, 0, 0, 0);
    }
    f32x4 accs = acc0 + acc1;
    // D layout: col=lane&15 (all equal), row=(lane>>4)*4+reg
    if (m == 0) *(f32x4*)&partials[wave][q * 4] = accs;
    __syncthreads();

    // ---- wave 0: reduce 4 k-partials per row, relu, publish via sc1 ----
    if (tid < ROWS_PER_WG) {
      int rbb = tid >> 4, rr = tid & 15;
      float s = partials[rbb * 4 + 0][rr] + partials[rbb * 4 + 1][rr] +
                partials[rbb * 4 + 2][rr] + partials[rbb * 4 + 3][rr];
      s = fmaxf(s, 0.f);
      int gr = wg * ROWS_PER_WG + tid;
      unsigned int hb = (unsigned int)__builtin_bit_cast(unsigned short, (_Float16)s);
      unsigned int up = __shfl_down(hb, 1);          // lanes 0..31 all computed hb
      if ((tid & 1) == 0) {
        unsigned int* dst = (unsigned int*)&g_ring[layer][t][0] + (gr >> 1);
        __hip_atomic_store(dst, hb | (up << 16),
                           __ATOMIC_RELAXED, __HIP_MEMORY_SCOPE_AGENT);
      }
      if (layer == NL - 1) {
        out[(size_t)t * HID + gr] = s;                      // output[0, t, :]
        if (t == SEQ - 1) out[(size_t)SEQ * HID + gr] = s;  // h_last
      }
    }
    // hand-rolled release: drain this wave's stores to the IC, then flag.
    asm volatile("s_waitcnt vmcnt(0)" ::: "memory");
    if (tid == 0)
      __hip_atomic_store(&g_flags[layer][wg], t + 1, __ATOMIC_RELAXED,
                         __HIP_MEMORY_SCOPE_AGENT);
  }
}

extern "C" void kernel_launch(void* const* d_in, const int* in_sizes, int n_in,
                              void* d_out, int out_size, void* d_ws, size_t ws_size,
                              hipStream_t stream) {
  const float* x   = (const float*)d_in[0];
  const float* wih = (const float*)d_in[1];
  const float* whh = (const float*)d_in[2];
  float* out = (float*)d_out;

  prep_kernel<<<(SEQ * HID + 1023) / 1024, 1024, 0, stream>>>(x);
  rnn_kernel<<<NL * WGS_PER_LAYER, 512, 0, stream>>>(wih, whh, out);
}

// Round 6
// 9828.892 us; speedup vs baseline: 14.9824x; 1.6964x over previous
//
#include <hip/hip_runtime.h>
#include <hip/hip_bf16.h>
#include <hip/hip_fp16.h>

// Persistent dataflow RNN for MI355X (gfx950).
//   SEQ=4096, HID=2048, 4 layers. 256 WGs (1 per CU), 64 per layer, 32 rows each.
//
// R6: single-round-trip handshake. R5's flag protocol cost ~4 serial IC round
// trips per superstep (store-drain, flag store, flag poll, data load). Now the
// DATA carries its own validity: each packed u32 (2 fp16) donates the LSB of
// its low fp16 as a step-parity tag. prep_kernel re-tags every (layer,t)
// region to the opposite parity before the RNN runs, so consumers poll their
// own data words until tags match (t&1) — the data load IS the poll, and the
// producer's single relaxed agent store IS the publication. No fences, no
// flags, no vmcnt drains in the loop. Numerics: +1 ulp on half the h elems.
// Design carried from R5: 512 thr (8 waves), __launch_bounds__(512,2), 128
// VGPRs/lane of pinned fp16 weight fragments, relaxed agent (sc1/IC) traffic.

#define SEQ 4096
#define HID 2048
#define NL 4
#define WGS_PER_LAYER 64
#define ROWS_PER_WG 32
#define KCAT 4096      // concat(x, h) elements
#define NT 32          // MFMA k-tiles per wave (k=1024 per wave, 4 k-ranges)

typedef _Float16 f16x8 __attribute__((ext_vector_type(8)));
typedef float f32x4 __attribute__((ext_vector_type(4)));
typedef unsigned long long u64;

__device__ __align__(16) _Float16 g_xin[(size_t)SEQ * HID];      // 16 MB
__device__ __align__(16) u64 g_ring[NL][SEQ][HID / 4];           // 67 MB (fp16 packed + tag LSBs)

// 8192 x 1024 = 8,388,608 = SEQ*HID = NL*SEQ*(HID/4) u64 — one grid does both.
__global__ void prep_kernel(const float* __restrict__ x) {
  size_t i = (size_t)blockIdx.x * blockDim.x + threadIdx.x;
  if (i < (size_t)SEQ * HID) g_xin[i] = (_Float16)x[i];
  if (i < (size_t)NL * SEQ * (HID / 4)) {
    size_t t = (i >> 9) & (SEQ - 1);                 // 512 u64 per (l,t) region
    unsigned int pat = (unsigned int)((t & 1) ^ 1);  // anti-parity tag
    u64 p64 = (u64)pat | ((u64)pat << 32);
    __hip_atomic_store(((u64*)g_ring) + i, p64, __ATOMIC_RELAXED,
                       __HIP_MEMORY_SCOPE_AGENT);    // sc1: visible at IC scope
  }
}

__global__ __launch_bounds__(512, 2) void rnn_kernel(
    const float* __restrict__ wih, const float* __restrict__ whh,
    float* __restrict__ out) {
  const int layer = blockIdx.x & 3;
  const int wg    = blockIdx.x >> 2;  // 0..63 within layer
  const int tid   = threadIdx.x;
  const int lane  = tid & 63;
  const int wave  = tid >> 6;         // 8 waves
  const int rb    = wave >> 2;        // row block: 0 -> rows 0..15, 1 -> 16..31
  const int kq    = wave & 3;         // k-range 0..3 (1024 k each)
  const int m     = lane & 15;
  const int q     = lane >> 4;
  const int row   = wg * ROWS_PER_WG + rb * 16 + m;

  __shared__ __align__(16) _Float16 cat[KCAT];      // [0,2048)=x_t [2048,4096)=h_{t-1}
  __shared__ __align__(16) float partials[8][16];   // [wave][row-in-16]

  // ---- one-time: weights -> registers as fp16 A-fragments (128 VGPRs) ----
  // A layout (16x16x32): lane holds A[m][ktile + q*8 + j], j=0..7
  f32x4 afrag[NT];
  {
    const float* wl = wih + (size_t)layer * HID * HID + (size_t)row * HID;
    const float* wr = whh + (size_t)layer * HID * HID + (size_t)row * HID - HID;
#pragma unroll
    for (int i = 0; i < NT; ++i) {
      int kabs = kq * 1024 + i * 32 + q * 8;   // 1024-aligned ranges: never straddle 2048
      const float* src = (kabs < HID) ? (wl + kabs) : (wr + kabs);
      f32x4 w0 = *(const f32x4*)(src);
      f32x4 w1 = *(const f32x4*)(src + 4);
      f16x8 a;
      a[0] = (_Float16)w0[0]; a[1] = (_Float16)w0[1];
      a[2] = (_Float16)w0[2]; a[3] = (_Float16)w0[3];
      a[4] = (_Float16)w1[0]; a[5] = (_Float16)w1[1];
      a[6] = (_Float16)w1[2]; a[7] = (_Float16)w1[3];
      afrag[i] = __builtin_bit_cast(f32x4, a);
    }
#pragma unroll
    for (int i = 0; i < NT; ++i) asm volatile("" : "+v"(afrag[i]));  // pin
  }

  for (int t = 0; t < SEQ; ++t) {
    // ---- stage concat(x_t, h_{t-1}): each wave independently poll-loads its
    //      16 B/lane until all tag bits match, then writes LDS. ----
    {
      u64 v0 = 0, v1 = 0;
      if (tid < 256) {
        if (layer == 0) {
          const u64* src = (const u64*)(g_xin + (size_t)t * HID);
          v0 = src[2 * tid];
          v1 = src[2 * tid + 1];
        } else {
          const u64* src = &g_ring[layer - 1][t][0];
          const u64 exp = (u64)(t & 1);
          int spin = 0;
          for (;;) {
            v0 = __hip_atomic_load(src + 2 * tid, __ATOMIC_RELAXED,
                                   __HIP_MEMORY_SCOPE_AGENT);
            v1 = __hip_atomic_load(src + 2 * tid + 1, __ATOMIC_RELAXED,
                                   __HIP_MEMORY_SCOPE_AGENT);
            bool ok = ((v0 & 1) == exp) && (((v0 >> 32) & 1) == exp) &&
                      ((v1 & 1) == exp) && (((v1 >> 32) & 1) == exp);
            if (__ballot(ok) == ~0ull) break;
            if (++spin > (1 << 20)) break;  // never hang the harness
            __builtin_amdgcn_s_sleep(1);
          }
        }
      } else if (t > 0) {
        const u64* src = &g_ring[layer][t - 1][0];
        const u64 exp = (u64)((t - 1) & 1);
        const int i = tid - 256;
        int spin = 0;
        for (;;) {
          v0 = __hip_atomic_load(src + 2 * i, __ATOMIC_RELAXED,
                                 __HIP_MEMORY_SCOPE_AGENT);
          v1 = __hip_atomic_load(src + 2 * i + 1, __ATOMIC_RELAXED,
                                 __HIP_MEMORY_SCOPE_AGENT);
          bool ok = ((v0 & 1) == exp) && (((v0 >> 32) & 1) == exp) &&
                    ((v1 & 1) == exp) && (((v1 >> 32) & 1) == exp);
          if (__ballot(ok) == ~0ull) break;
          if (++spin > (1 << 20)) break;
          __builtin_amdgcn_s_sleep(1);
        }
      }
      ((u64*)cat)[2 * tid]     = v0;
      ((u64*)cat)[2 * tid + 1] = v1;
    }
    __syncthreads();

    // ---- MFMA: 16 rows x own 1024-k range. B = h broadcast to 16 cols ----
    f32x4 acc0 = {0.f, 0.f, 0.f, 0.f}, acc1 = {0.f, 0.f, 0.f, 0.f};
    const f16x8* bb = (const f16x8*)cat;
#pragma unroll
    for (int i = 0; i < NT; i += 2) {
      f16x8 b0 = bb[kq * 128 + i * 4 + q];
      f16x8 b1 = bb[kq * 128 + (i + 1) * 4 + q];
      acc0 = __builtin_amdgcn_mfma_f32_16x16x32_f16(
          __builtin_bit_cast(f16x8, afrag[i]), b0, acc0, 0, 0, 0);
      acc1 = __builtin_amdgcn_mfma_f32_16x16x32_f16(
          __builtin_bit_cast(f16x8, afrag[i + 1]), b1, acc1, 0, 0, 0);
    }
    f32x4 accs = acc0 + acc1;
    // D layout: col=lane&15 (all equal), row=(lane>>4)*4+reg
    if (m == 0) *(f32x4*)&partials[wave][q * 4] = accs;
    __syncthreads();

    // ---- wave 0: reduce 4 k-partials per row, relu, publish (store == flag) ----
    if (tid < ROWS_PER_WG) {
      int rbb = tid >> 4, rr = tid & 15;
      float s = partials[rbb * 4 + 0][rr] + partials[rbb * 4 + 1][rr] +
                partials[rbb * 4 + 2][rr] + partials[rbb * 4 + 3][rr];
      s = fmaxf(s, 0.f);
      int gr = wg * ROWS_PER_WG + tid;
      if (layer == NL - 1) {
        out[(size_t)t * HID + gr] = s;                      // output[0, t, :]
        if (t == SEQ - 1) out[(size_t)SEQ * HID + gr] = s;  // h_last
      }
      unsigned int hb = (unsigned int)__builtin_bit_cast(unsigned short, (_Float16)s);
      unsigned int up = __shfl_down(hb, 1);          // odd row's bits
      if ((tid & 1) == 0) {
        unsigned int word = (hb & 0xFFFEu) | (unsigned int)(t & 1) | (up << 16);
        unsigned int* dst = (unsigned int*)&g_ring[layer][t][0] + (gr >> 1);
        __hip_atomic_store(dst, word, __ATOMIC_RELAXED, __HIP_MEMORY_SCOPE_AGENT);
      }
    }
    // no drain, no flag: the tagged store above is the publication.
  }
}

extern "C" void kernel_launch(void* const* d_in, const int* in_sizes, int n_in,
                              void* d_out, int out_size, void* d_ws, size_t ws_size,
                              hipStream_t stream) {
  const float* x   = (const float*)d_in[0];
  const float* wih = (const float*)d_in[1];
  const float* whh = (const float*)d_in[2];
  float* out = (float*)d_out;

  prep_kernel<<<8192, 1024, 0, stream>>>(x);
  rnn_kernel<<<NL * WGS_PER_LAYER, 512, 0, stream>>>(wih, whh, out);
}